// Round 3
// baseline (286.966 us; speedup 1.0000x reference)
//
#include <hip/hip_runtime.h>
#include <math.h>

#define F_ 48
#define C_ 128
#define HW 16384
#define SCALE_C 0.999f
#define TPB 256      // setup kernels
#define MTPB 512     // main kernel: 8 waves/block

typedef __attribute__((ext_vector_type(4))) float floatx4;
typedef __attribute__((ext_vector_type(8))) _Float16 half8;
typedef __attribute__((ext_vector_type(4))) _Float16 half4;

// ---- ws layout ----
// ushort region:
//   P1 frags (f16): [mtile(24)][ks(4)][lane(64)][j(8)] = 49152 ushorts
//     even mtile = Wf rows (v), odd mtile = (Qeq.Wf) rows (y), paired per f-group
//   P2 frags (f16): [cmt(8)][ks(12)][lane(64)][j(8)] = 49152 ushorts at 49152
//     ks 0..5 = Wf^T (u part), ks 6..11 = -(SCALE*Qm)^T-folded Wf (m2 part)
// float region at float offset 49152 (byte 196608):
#define P1_U 0
#define P2_U 49152
#define QEQN_F 49152              // [48][32]: [0..15]=Qeq[l][g], [16..31]=SCALE*Qm[a][b]
#define MISC_F (QEQN_F + 1536)    // eps_e, invden
#define SINV_F (MISC_F + 2)       // [2][48] 1/scaling
#define SLAM_F (SINV_F + 96)      // [2][48] lamb_e*scaling

// ---------------- setup: math (1 block, tiny) ----------------
__global__ void setup_math(const float* __restrict__ sigma,
                           const float* __restrict__ Qp,
                           const float* __restrict__ taus_p,
                           const float* __restrict__ lamb,
                           const float* __restrict__ eps_om,
                           const float* __restrict__ mw1, const float* __restrict__ mb1,
                           const float* __restrict__ mw2, const float* __restrict__ mb2,
                           const float* __restrict__ mw3, const float* __restrict__ mb3,
                           float* __restrict__ wsf)
{
    const int tid = threadIdx.x;
    if (tid < F_) {
        const int f = tid;
        float Qm[4][4];
        for (int g = 0; g < 4; ++g) {
            float s = 0.f;
            for (int l = 0; l < 4; ++l) s += fabsf(Qp[f * 16 + g * 4 + l]);
            float d = fmaxf(s, 1.0f);
            for (int l = 0; l < 4; ++l) Qm[g][l] = Qp[f * 16 + g * 4 + l] / d;
        }
        double A[4][4];
        for (int i = 0; i < 4; ++i)
            for (int j = 0; j < 4; ++j) {
                double s = 0.0;
                for (int g = 0; g < 4; ++g) s += (double)Qm[g][i] * (double)Qm[g][j];
                A[i][j] = s;
            }
        double M[4][4];
        for (int i = 0; i < 4; ++i) for (int j = 0; j < 4; ++j) M[i][j] = A[i][j];
        for (int it = 0; it < 30; ++it) {
            double T[4][4]; double mx = 0.0;
            for (int i = 0; i < 4; ++i)
                for (int j = 0; j < 4; ++j) {
                    double s = 0.0;
                    for (int k = 0; k < 4; ++k) s += M[i][k] * M[k][j];
                    T[i][j] = s;
                    double a = fabs(s); if (a > mx) mx = a;
                }
            if (mx < 1e-300) break;
            double inv = 1.0 / mx;
            for (int i = 0; i < 4; ++i) for (int j = 0; j < 4; ++j) M[i][j] = T[i][j] * inv;
        }
        int jb = 0; double bn = -1.0;
        for (int j = 0; j < 4; ++j) {
            double nn = 0.0;
            for (int i = 0; i < 4; ++i) nn += M[i][j] * M[i][j];
            if (nn > bn) { bn = nn; jb = j; }
        }
        double v[4]; for (int i = 0; i < 4; ++i) v[i] = M[i][jb];
        double Av[4];
        for (int i = 0; i < 4; ++i) {
            double s = 0.0;
            for (int j = 0; j < 4; ++j) s += A[i][j] * v[j];
            Av[i] = s;
        }
        double vv = 0.0, vav = 0.0;
        for (int i = 0; i < 4; ++i) { vv += v[i] * v[i]; vav += v[i] * Av[i]; }
        float lamf = (float)((vv > 0.0) ? (vav / vv) : 0.0);
        float tau = expf(fmaxf(taus_p[f], 0.0f));
        float qsv = SCALE_C / tau;
        for (int l = 0; l < 4; ++l)
            for (int g = 0; g < 4; ++g)
                wsf[QEQN_F + f * 32 + l * 4 + g] = qsv * Qm[l][g] / lamf;
        for (int g = 0; g < 4; ++g)
            for (int l = 0; l < 4; ++l)
                wsf[QEQN_F + f * 32 + 16 + g * 4 + l] = SCALE_C * Qm[g][l];
    }
    if (tid >= 48 && tid < 50) {
        const int b = tid - 48;
        float lamb_e = expf(lamb[0]);
        float sg = sigma[b];
        float t = sg * 20.0f - 2.0f;
        float h1[F_], h2[F_];
        for (int j = 0; j < F_; ++j) h1[j] = fmaxf(t * mw1[j] + mb1[j], 0.0f);
        for (int j = 0; j < F_; ++j) {
            float s = mb2[j];
            for (int k = 0; k < F_; ++k) s += h1[k] * mw2[k * F_ + j];
            h2[j] = fmaxf(s, 0.0f);
        }
        for (int j = 0; j < F_; ++j) {
            float s = mb3[j];
            for (int k = 0; k < F_; ++k) s += h2[k] * mw3[k * F_ + j];
            float sc = fmaxf(s * 0.05f + sg, 0.0f) + 1e-9f;
            wsf[SINV_F + b * F_ + j] = 1.0f / sc;
            wsf[SLAM_F + b * F_ + j] = lamb_e * sc;
        }
    }
    if (tid == 50) {
        float lamb_e = expf(lamb[0]);
        float eps_e = expf(eps_om[0]);
        wsf[MISC_F + 0] = eps_e;
        wsf[MISC_F + 1] = 1.0f / (1.0f + lamb_e * (1.0f + eps_e));
    }
}

// ---------------- setup: fragment packing (grid-parallel; AFTER setup_math) ----------------
__global__ void setup_pack(const float* __restrict__ Wf, float* __restrict__ wsf)
{
    unsigned short* wsu = (unsigned short*)wsf;
    const int gtid = blockIdx.x * TPB + threadIdx.x;
    for (int i = gtid; i < 98304; i += gridDim.x * TPB) {
        if (i < 49152) {
            // pass-1 A frags: 24 mtiles. even = Wf (v-rows), odd = Qeq.Wf (y-rows)
            int j = i & 7, lane = (i >> 3) & 63;
            int t = i >> 9;                // 0..95
            int ks = t & 3, mtile = t >> 2;
            int rt = lane & 15, qq = lane >> 4;
            int c = ks * 32 + qq * 8 + j;
            int ft = mtile >> 1;
            int f = ft * 4 + (rt >> 2);
            int gl = rt & 3;
            float w;
            if ((mtile & 1) == 0) {
                w = Wf[(gl * F_ + f) * C_ + c];
            } else {
                w = 0.f;
                for (int g = 0; g < 4; ++g)
                    w += wsf[QEQN_F + f * 32 + gl * 4 + g] * Wf[(g * F_ + f) * C_ + c];
            }
            _Float16 hv = (_Float16)w;
            wsu[P1_U + ((mtile * 4 + ks) * 64 + lane) * 8 + j] = *(unsigned short*)&hv;
        } else {
            // pass-2 A frags: K=384. ks<6: Wf^T (u part); ks>=6: -(SCALE*Qm)^T fold (m2 part)
            int ii = i - 49152;
            int j = ii & 7, lane = (ii >> 3) & 63;
            int t = ii >> 9;               // 0..95
            int ks = t % 12, cmt = t / 12;
            int m = lane & 15, qq = lane >> 4;
            int cch = cmt * 16 + m;
            int r = ks * 32 + qq * 8 + j;  // 0..383
            float w;
            if (ks < 6) {
                int f = r >> 2, g = r & 3;
                w = Wf[(g * F_ + f) * C_ + cch];
            } else {
                int rp = r - 192;
                int f = rp >> 2, l = rp & 3;
                w = 0.f;
                for (int g = 0; g < 4; ++g)
                    w += wsf[QEQN_F + f * 32 + 16 + l * 4 + g] * Wf[(g * F_ + f) * C_ + cch];
                w = -w;
            }
            _Float16 hv = (_Float16)w;
            wsu[P2_U + ((cmt * 12 + ks) * 64 + lane) * 8 + j] = *(unsigned short*)&hv;
        }
    }
}

// Euclidean projection of a 4-vector onto the unit l1 ball (per lane, in regs)
// divide replaced by reciprocal-constant select (rh in {1,2,3,4})
__device__ __forceinline__ void proj4(const float v[4], float o[4]) {
    float a0 = fabsf(v[0]), a1 = fabsf(v[1]), a2 = fabsf(v[2]), a3 = fabsf(v[3]);
    float sum = a0 + a1 + a2 + a3;
    float t0 = fmaxf(a0, a1), u0 = fminf(a0, a1);
    float t1 = fmaxf(a2, a3), u1 = fminf(a2, a3);
    float s0 = fmaxf(t0, t1), m0 = fminf(t0, t1);
    float m1 = fmaxf(u0, u1), s3 = fminf(u0, u1);
    float s1 = fmaxf(m1, m0), s2 = fminf(m1, m0);
    float c2 = s0 + s1, c3 = c2 + s2, c4 = c3 + s3;
    float th = s0 - 1.0f, rs = 1.0f;
    if (s1 * 2.0f > c2 - 1.0f) { th = c2 - 1.0f; rs = 0.5f; }
    if (s2 * 3.0f > c3 - 1.0f) { th = c3 - 1.0f; rs = (1.0f / 3.0f); }
    if (s3 * 4.0f > c4 - 1.0f) { th = c4 - 1.0f; rs = 0.25f; }
    float theta = fmaxf(th * rs, 0.0f);
    bool inside = (sum <= 1.0f);
#pragma unroll
    for (int g = 0; g < 4; ++g) {
        float ag = fabsf(v[g]);
        float pg = copysignf(fmaxf(ag - theta, 0.0f), v[g]);
        o[g] = inside ? v[g] : pg;
    }
}

// ---------------- main: 32-pixel tile, 8 waves/block, 1024 blocks ----------------
// sXF/sACT in MFMA-fragment order [nt][ks][lane][8] (stride-1 ds_read_b128).
// Pass-1 M=384 (v+y in paired tiles, shared B); pass-2 K=384 (u and m2 parts).
__global__ __launch_bounds__(MTPB, 4) void mfoe_main(
    const float* __restrict__ xnoisy,
    const float* __restrict__ wsf,
    float* __restrict__ out,
    const int* __restrict__ n_iter_p)
{
    __shared__ __align__(16) _Float16 sXF[4096];    // [nt(2)][ks(4)][lane(64)][j(8)]
    __shared__ __align__(16) _Float16 sACT[12288];  // [nt(2)][ks(12)][lane(64)][j(8)]
    __shared__ __align__(16) float sISL[96];        // [0..47]=invs, [48..95]=slam

    const int tid = threadIdx.x;
    const int lane = tid & 63;
    const int wv = __builtin_amdgcn_readfirstlane(tid >> 6);   // SGPR wave id, 0..7
    const int n = lane & 15;
    const int q = lane >> 4;
    const int blk = blockIdx.x;
    const int b = blk >> 9;                 // 512 blocks per image
    const int pix0 = (blk & 511) << 5;      // 32 pixels per block

    const float* __restrict__ xin = xnoisy + b * (C_ * HW) + pix0;
    float* __restrict__ oimg = out + b * (C_ * HW) + pix0;
    const unsigned short* __restrict__ wsu = (const unsigned short*)wsf;
    const int niter = *n_iter_p;

    if (niter == 0) {
        for (int i = tid; i < C_ * 32; i += MTPB) {
            int p = i & 31, c = i >> 5;
            oimg[c * HW + p] = xin[c * HW + p];
        }
        return;
    }

    // stage x -> LDS f16 in fragment order
    for (int i = tid; i < C_ * 32; i += MTPB) {
        int p = i & 31, c = i >> 5;
        int idx = ((p >> 4) * 4 + (c >> 5)) * 512 + (((c >> 3) & 3) * 16 + (p & 15)) * 8 + (c & 7);
        sXF[idx] = (_Float16)xin[c * HW + p];
    }
    // stage invs/slam
    for (int i = tid; i < 96; i += MTPB) {
        if (i < 48) sISL[i] = wsf[SINV_F + b * F_ + i];
        else        sISL[i] = wsf[SLAM_F + b * F_ + (i - 48)];
    }

    // preload this thread's x_noisy values (update layout): 2 jobs x 4 channels
    float xnr[8];
#pragma unroll
    for (int j = 0; j < 2; ++j) {
        int jw = wv * 2 + j, cmt = jw >> 1, nt = jw & 1;
        int p = nt * 16 + n;
#pragma unroll
        for (int reg = 0; reg < 4; ++reg)
            xnr[j * 4 + reg] = xin[(cmt * 16 + q * 4 + reg) * HW + p];
    }
    const float eps_e = wsf[MISC_F + 0];
    const float invden = wsf[MISC_F + 1];

    for (int it = 0; it < niter; ++it) {
        __syncthreads();   // x ready (and sISL on iter 0)
        // ---- pass 1: 24 paired jobs (ft 0..11, nt 0..1), 3 per wave
#pragma unroll 1
        for (int j = 0; j < 3; ++j) {
            int jw = wv * 3 + j, ft = jw >> 1, nt = jw & 1;
            floatx4 accv = (floatx4){0.f, 0.f, 0.f, 0.f};
            floatx4 accy = (floatx4){0.f, 0.f, 0.f, 0.f};
            const half8* aE = (const half8*)(wsu + P1_U + (ft * 8) * 512 + lane * 8);
            const half8* bFp = (const half8*)&sXF[nt * 2048 + lane * 8];
#pragma unroll
            for (int ks = 0; ks < 4; ++ks) {
                half8 bF = bFp[ks * 64];
                accv = __builtin_amdgcn_mfma_f32_16x16x32_f16(aE[ks * 64], bF, accv, 0, 0, 0);
                accy = __builtin_amdgcn_mfma_f32_16x16x32_f16(aE[ks * 64 + 256], bF, accy, 0, 0, 0);
            }
            // ---- activation: lane owns (f = ft*4+q, pixel p); v and y both in regs
            int f = ft * 4 + q;
            float invs = sISL[f];
            float slam = sISL[48 + f];
            float v[4] = {accv[0] * invs, accv[1] * invs, accv[2] * invs, accv[3] * invs};
            float y[4] = {accy[0] * invs, accy[1] * invs, accy[2] * invs, accy[3] * invs};
            float pv[4]; proj4(v, pv);
            float py[4]; proj4(y, py);
            half4 au, am;
#pragma unroll
            for (int g = 0; g < 4; ++g) {
                au[g] = (_Float16)(fmaf(eps_e, v[g], pv[g]) * slam);
                am[g] = (_Float16)(fmaf(eps_e, y[g], py[g]) * slam);
            }
            // act rows r = ft*16 + q*4 + l -> frag slot; m2 part 6 ks-tiles later
            int aw = ((nt * 12 + (ft >> 1)) * 64 + ((ft & 1) * 2 + (q >> 1)) * 16 + n) * 8 + (q & 1) * 4;
            *(half4*)&sACT[aw] = au;
            *(half4*)&sACT[aw + 3072] = am;
        }
        __syncthreads();   // act ready; all pass-1 x reads done
        // ---- pass 2: 16 (cmt,nt) jobs, 2 per wave, K=384
        floatx4 acc2[2];
#pragma unroll
        for (int j = 0; j < 2; ++j) acc2[j] = (floatx4){0.f, 0.f, 0.f, 0.f};
#pragma unroll
        for (int j = 0; j < 2; ++j) {
            int jw = wv * 2 + j, cmt = jw >> 1, nt = jw & 1;
            const half8* a2F = (const half8*)(wsu + P2_U + (cmt * 12) * 512 + lane * 8);
            const half8* bAp = (const half8*)&sACT[nt * 6144 + lane * 8];
            floatx4 a = acc2[j];
#pragma unroll
            for (int ks = 0; ks < 12; ++ks) {
                half8 aF = a2F[ks * 64];
                half8 bA = bAp[ks * 64];
                a = __builtin_amdgcn_mfma_f32_16x16x32_f16(aF, bA, a, 0, 0, 0);
            }
            acc2[j] = a;
        }
        // ---- update: thread owns (cmt,q,nt) cells; x kept as single f16
        const bool last = (it == niter - 1);
#pragma unroll
        for (int j = 0; j < 2; ++j) {
            int jw = wv * 2 + j, cmt = jw >> 1, nt = jw & 1;
            int p = nt * 16 + n;
            int cb = cmt * 16 + q * 4;
            int xu = ((nt * 4 + (cmt >> 1)) * 64 + ((cmt & 1) * 2 + (q >> 1)) * 16 + n) * 8 + (q & 1) * 4;
            half4 xo4 = *(const half4*)&sXF[xu];
            float xo0 = (float)xo4[0];
            float xo1 = (float)xo4[1];
            float xo2 = (float)xo4[2];
            float xo3 = (float)xo4[3];
            float nx0 = xo0 - ((xo0 - xnr[j * 4 + 0]) + acc2[j][0]) * invden;
            float nx1 = xo1 - ((xo1 - xnr[j * 4 + 1]) + acc2[j][1]) * invden;
            float nx2 = xo2 - ((xo2 - xnr[j * 4 + 2]) + acc2[j][2]) * invden;
            float nx3 = xo3 - ((xo3 - xnr[j * 4 + 3]) + acc2[j][3]) * invden;
            if (last) {
                oimg[(cb + 0) * HW + p] = nx0;
                oimg[(cb + 1) * HW + p] = nx1;
                oimg[(cb + 2) * HW + p] = nx2;
                oimg[(cb + 3) * HW + p] = nx3;
            }
            half4 nx4;
            nx4[0] = (_Float16)nx0;
            nx4[1] = (_Float16)nx1;
            nx4[2] = (_Float16)nx2;
            nx4[3] = (_Float16)nx3;
            *(half4*)&sXF[xu] = nx4;
        }
    }
}

extern "C" void kernel_launch(void* const* d_in, const int* in_sizes, int n_in,
                              void* d_out, int out_size, void* d_ws, size_t ws_size,
                              hipStream_t stream) {
    const float* x_noisy = (const float*)d_in[0];
    const float* sigma   = (const float*)d_in[1];
    const float* Qp      = (const float*)d_in[2];
    const float* taus_p  = (const float*)d_in[3];
    const float* lamb    = (const float*)d_in[4];
    const float* eps_om  = (const float*)d_in[5];
    const float* mw1     = (const float*)d_in[6];
    const float* mb1     = (const float*)d_in[7];
    const float* mw2     = (const float*)d_in[8];
    const float* mb2     = (const float*)d_in[9];
    const float* mw3     = (const float*)d_in[10];
    const float* mb3     = (const float*)d_in[11];
    const float* Wf      = (const float*)d_in[12];
    const int*   n_iter  = (const int*)d_in[13];
    float* out = (float*)d_out;
    float* ws  = (float*)d_ws;

    hipLaunchKernelGGL(setup_math, dim3(1), dim3(64), 0, stream,
                       sigma, Qp, taus_p, lamb, eps_om,
                       mw1, mb1, mw2, mb2, mw3, mb3, ws);
    hipLaunchKernelGGL(setup_pack, dim3(192), dim3(TPB), 0, stream, Wf, ws);
    hipLaunchKernelGGL(mfoe_main, dim3(1024), dim3(MTPB), 0, stream,
                       x_noisy, ws, out, n_iter);
}

// Round 4
// 283.696 us; speedup vs baseline: 1.0115x; 1.0115x over previous
//
#include <hip/hip_runtime.h>
#include <math.h>

#define F_ 48
#define C_ 128
#define HW 16384
#define SCALE_C 0.999f
#define TPB 256      // setup kernels
#define MTPB 512     // main kernel: 8 waves/block

typedef __attribute__((ext_vector_type(4))) float floatx4;
typedef __attribute__((ext_vector_type(8))) _Float16 half8;
typedef __attribute__((ext_vector_type(4))) _Float16 half4;

// ---- ws layout ----
// ushort region:
//   P1 frags (f16): [mtile(24)][ks(4)][lane(64)][j(8)] = 49152 ushorts
//     even mtile = Wf rows (v), odd mtile = (Qeq.Wf) rows (y), paired per f-group
//   P2 frags (f16): [cmt(8)][ks(12)][lane(64)][j(8)] = 49152 ushorts at 49152
//     ks 0..5 = Wf^T (u part), ks 6..11 = -(SCALE*Qm)^T-folded Wf (m2 part)
// float region at float offset 49152 (byte 196608):
#define P1_U 0
#define P2_U 49152
#define QEQN_F 49152              // [48][32]: [0..15]=Qeq[l][g], [16..31]=SCALE*Qm[a][b]
#define MISC_F (QEQN_F + 1536)    // eps_e, invden
#define SINV_F (MISC_F + 2)       // [2][48] 1/scaling
#define SLAM_F (SINV_F + 96)      // [2][48] lamb_e*scaling

// ---------------- setup: math (1 block, tiny) ----------------
__global__ void setup_math(const float* __restrict__ sigma,
                           const float* __restrict__ Qp,
                           const float* __restrict__ taus_p,
                           const float* __restrict__ lamb,
                           const float* __restrict__ eps_om,
                           const float* __restrict__ mw1, const float* __restrict__ mb1,
                           const float* __restrict__ mw2, const float* __restrict__ mb2,
                           const float* __restrict__ mw3, const float* __restrict__ mb3,
                           float* __restrict__ wsf)
{
    const int tid = threadIdx.x;
    if (tid < F_) {
        const int f = tid;
        float Qm[4][4];
        for (int g = 0; g < 4; ++g) {
            float s = 0.f;
            for (int l = 0; l < 4; ++l) s += fabsf(Qp[f * 16 + g * 4 + l]);
            float d = fmaxf(s, 1.0f);
            for (int l = 0; l < 4; ++l) Qm[g][l] = Qp[f * 16 + g * 4 + l] / d;
        }
        double A[4][4];
        for (int i = 0; i < 4; ++i)
            for (int j = 0; j < 4; ++j) {
                double s = 0.0;
                for (int g = 0; g < 4; ++g) s += (double)Qm[g][i] * (double)Qm[g][j];
                A[i][j] = s;
            }
        double M[4][4];
        for (int i = 0; i < 4; ++i) for (int j = 0; j < 4; ++j) M[i][j] = A[i][j];
        for (int it = 0; it < 30; ++it) {
            double T[4][4]; double mx = 0.0;
            for (int i = 0; i < 4; ++i)
                for (int j = 0; j < 4; ++j) {
                    double s = 0.0;
                    for (int k = 0; k < 4; ++k) s += M[i][k] * M[k][j];
                    T[i][j] = s;
                    double a = fabs(s); if (a > mx) mx = a;
                }
            if (mx < 1e-300) break;
            double inv = 1.0 / mx;
            for (int i = 0; i < 4; ++i) for (int j = 0; j < 4; ++j) M[i][j] = T[i][j] * inv;
        }
        int jb = 0; double bn = -1.0;
        for (int j = 0; j < 4; ++j) {
            double nn = 0.0;
            for (int i = 0; i < 4; ++i) nn += M[i][j] * M[i][j];
            if (nn > bn) { bn = nn; jb = j; }
        }
        double v[4]; for (int i = 0; i < 4; ++i) v[i] = M[i][jb];
        double Av[4];
        for (int i = 0; i < 4; ++i) {
            double s = 0.0;
            for (int j = 0; j < 4; ++j) s += A[i][j] * v[j];
            Av[i] = s;
        }
        double vv = 0.0, vav = 0.0;
        for (int i = 0; i < 4; ++i) { vv += v[i] * v[i]; vav += v[i] * Av[i]; }
        float lamf = (float)((vv > 0.0) ? (vav / vv) : 0.0);
        float tau = expf(fmaxf(taus_p[f], 0.0f));
        float qsv = SCALE_C / tau;
        for (int l = 0; l < 4; ++l)
            for (int g = 0; g < 4; ++g)
                wsf[QEQN_F + f * 32 + l * 4 + g] = qsv * Qm[l][g] / lamf;
        for (int g = 0; g < 4; ++g)
            for (int l = 0; l < 4; ++l)
                wsf[QEQN_F + f * 32 + 16 + g * 4 + l] = SCALE_C * Qm[g][l];
    }
    if (tid >= 48 && tid < 50) {
        const int b = tid - 48;
        float lamb_e = expf(lamb[0]);
        float sg = sigma[b];
        float t = sg * 20.0f - 2.0f;
        float h1[F_], h2[F_];
        for (int j = 0; j < F_; ++j) h1[j] = fmaxf(t * mw1[j] + mb1[j], 0.0f);
        for (int j = 0; j < F_; ++j) {
            float s = mb2[j];
            for (int k = 0; k < F_; ++k) s += h1[k] * mw2[k * F_ + j];
            h2[j] = fmaxf(s, 0.0f);
        }
        for (int j = 0; j < F_; ++j) {
            float s = mb3[j];
            for (int k = 0; k < F_; ++k) s += h2[k] * mw3[k * F_ + j];
            float sc = fmaxf(s * 0.05f + sg, 0.0f) + 1e-9f;
            wsf[SINV_F + b * F_ + j] = 1.0f / sc;
            wsf[SLAM_F + b * F_ + j] = lamb_e * sc;
        }
    }
    if (tid == 50) {
        float lamb_e = expf(lamb[0]);
        float eps_e = expf(eps_om[0]);
        wsf[MISC_F + 0] = eps_e;
        wsf[MISC_F + 1] = 1.0f / (1.0f + lamb_e * (1.0f + eps_e));
    }
}

// ---------------- setup: fragment packing (grid-parallel; AFTER setup_math) ----------------
__global__ void setup_pack(const float* __restrict__ Wf, float* __restrict__ wsf)
{
    unsigned short* wsu = (unsigned short*)wsf;
    const int gtid = blockIdx.x * TPB + threadIdx.x;
    for (int i = gtid; i < 98304; i += gridDim.x * TPB) {
        if (i < 49152) {
            // pass-1 A frags: 24 mtiles. even = Wf (v-rows), odd = Qeq.Wf (y-rows)
            int j = i & 7, lane = (i >> 3) & 63;
            int t = i >> 9;                // 0..95
            int ks = t & 3, mtile = t >> 2;
            int rt = lane & 15, qq = lane >> 4;
            int c = ks * 32 + qq * 8 + j;
            int ft = mtile >> 1;
            int f = ft * 4 + (rt >> 2);
            int gl = rt & 3;
            float w;
            if ((mtile & 1) == 0) {
                w = Wf[(gl * F_ + f) * C_ + c];
            } else {
                w = 0.f;
                for (int g = 0; g < 4; ++g)
                    w += wsf[QEQN_F + f * 32 + gl * 4 + g] * Wf[(g * F_ + f) * C_ + c];
            }
            _Float16 hv = (_Float16)w;
            wsu[P1_U + ((mtile * 4 + ks) * 64 + lane) * 8 + j] = *(unsigned short*)&hv;
        } else {
            // pass-2 A frags: K=384. ks<6: Wf^T (u part); ks>=6: -(SCALE*Qm)^T fold (m2 part)
            int ii = i - 49152;
            int j = ii & 7, lane = (ii >> 3) & 63;
            int t = ii >> 9;               // 0..95
            int ks = t % 12, cmt = t / 12;
            int m = lane & 15, qq = lane >> 4;
            int cch = cmt * 16 + m;
            int r = ks * 32 + qq * 8 + j;  // 0..383
            float w;
            if (ks < 6) {
                int f = r >> 2, g = r & 3;
                w = Wf[(g * F_ + f) * C_ + cch];
            } else {
                int rp = r - 192;
                int f = rp >> 2, l = rp & 3;
                w = 0.f;
                for (int g = 0; g < 4; ++g)
                    w += wsf[QEQN_F + f * 32 + 16 + l * 4 + g] * Wf[(g * F_ + f) * C_ + cch];
                w = -w;
            }
            _Float16 hv = (_Float16)w;
            wsu[P2_U + ((cmt * 12 + ks) * 64 + lane) * 8 + j] = *(unsigned short*)&hv;
        }
    }
}

// Euclidean projection of a 4-vector onto the unit l1 ball (per lane, in regs)
__device__ __forceinline__ void proj4(const float v[4], float o[4]) {
    float a0 = fabsf(v[0]), a1 = fabsf(v[1]), a2 = fabsf(v[2]), a3 = fabsf(v[3]);
    float sum = a0 + a1 + a2 + a3;
    float t0 = fmaxf(a0, a1), u0 = fminf(a0, a1);
    float t1 = fmaxf(a2, a3), u1 = fminf(a2, a3);
    float s0 = fmaxf(t0, t1), m0 = fminf(t0, t1);
    float m1 = fmaxf(u0, u1), s3 = fminf(u0, u1);
    float s1 = fmaxf(m1, m0), s2 = fminf(m1, m0);
    float c2 = s0 + s1, c3 = c2 + s2, c4 = c3 + s3;
    float th = s0 - 1.0f, rs = 1.0f;
    if (s1 * 2.0f > c2 - 1.0f) { th = c2 - 1.0f; rs = 0.5f; }
    if (s2 * 3.0f > c3 - 1.0f) { th = c3 - 1.0f; rs = (1.0f / 3.0f); }
    if (s3 * 4.0f > c4 - 1.0f) { th = c4 - 1.0f; rs = 0.25f; }
    float theta = fmaxf(th * rs, 0.0f);
    bool inside = (sum <= 1.0f);
#pragma unroll
    for (int g = 0; g < 4; ++g) {
        float ag = fabsf(v[g]);
        float pg = copysignf(fmaxf(ag - theta, 0.0f), v[g]);
        o[g] = inside ? v[g] : pg;
    }
}

// ---------------- main: 64-pixel tile, 8 waves/block, 512 blocks ----------------
// A-fragments (weights, iteration-invariant, L2-resident) are amortized over
// multiple pixel tiles: pass-1 reuses each A over 2 np tiles, pass-2 over 4.
// x kept in registers across iterations (f32); sXF is write-by-update/read-by-pass1.
__global__ __launch_bounds__(MTPB, 4) void mfoe_main(
    const float* __restrict__ xnoisy,
    const float* __restrict__ wsf,
    float* __restrict__ out,
    const int* __restrict__ n_iter_p)
{
    __shared__ __align__(16) _Float16 sXF[8192];    // [np(4)][ks(4)][lane(64)][j(8)]
    __shared__ __align__(16) _Float16 sACT[24576];  // [np(4)][ks(12)][lane(64)][j(8)]
    __shared__ __align__(16) float sISL[96];        // [0..47]=invs, [48..95]=slam

    const int tid = threadIdx.x;
    const int lane = tid & 63;
    const int wv = __builtin_amdgcn_readfirstlane(tid >> 6);   // SGPR wave id, 0..7
    const int n = lane & 15;
    const int q = lane >> 4;
    const int blk = blockIdx.x;
    const int b = blk >> 8;                 // 256 blocks per image
    const int pix0 = (blk & 255) << 6;      // 64 pixels per block

    const float* __restrict__ xin = xnoisy + b * (C_ * HW) + pix0;
    float* __restrict__ oimg = out + b * (C_ * HW) + pix0;
    const unsigned short* __restrict__ wsu = (const unsigned short*)wsf;
    const int niter = *n_iter_p;

    if (niter == 0) {
        for (int i = tid; i < C_ * 64; i += MTPB) {
            int p = i & 63, c = i >> 6;
            oimg[c * HW + p] = xin[c * HW + p];
        }
        return;
    }

    // stage x -> LDS f16 in fragment order
    for (int i = tid; i < C_ * 64; i += MTPB) {
        int p = i & 63, c = i >> 6;
        int idx = (((p >> 4) * 4 + (c >> 5)) * 64 + ((c >> 3) & 3) * 16 + (p & 15)) * 8 + (c & 7);
        sXF[idx] = (_Float16)xin[c * HW + p];
    }
    // stage invs/slam
    for (int i = tid; i < 96; i += MTPB) {
        if (i < 48) sISL[i] = wsf[SINV_F + b * F_ + i];
        else        sISL[i] = wsf[SLAM_F + b * F_ + (i - 48)];
    }

    // x_noisy + running x in registers: thread owns channels wv*16+q*4..+3, pixels np*16+n
    float xnr[16], xr[16];
#pragma unroll
    for (int np = 0; np < 4; ++np)
#pragma unroll
        for (int l = 0; l < 4; ++l) {
            float v = xin[(wv * 16 + q * 4 + l) * HW + np * 16 + n];
            xnr[np * 4 + l] = v;
            xr[np * 4 + l] = v;
        }
    const float eps_e = wsf[MISC_F + 0];
    const float invden = wsf[MISC_F + 1];

    for (int it = 0; it < niter; ++it) {
        __syncthreads();   // x ready (and sISL on iter 0)
        // ---- pass 1: 24 groups (ft 0..11, nph 0..1), 3 per wave; A reused over 2 np
#pragma unroll 1
        for (int jj = 0; jj < 3; ++jj) {
            int grp = wv * 3 + jj, ft = grp >> 1, nph = grp & 1;
            int np0 = nph * 2;
            floatx4 accv0 = (floatx4){0.f, 0.f, 0.f, 0.f};
            floatx4 accv1 = (floatx4){0.f, 0.f, 0.f, 0.f};
            floatx4 accy0 = (floatx4){0.f, 0.f, 0.f, 0.f};
            floatx4 accy1 = (floatx4){0.f, 0.f, 0.f, 0.f};
            const half8* aE = (const half8*)(wsu + P1_U + (ft * 8) * 512 + lane * 8);
            const half8* b0 = (const half8*)&sXF[(np0 * 4) * 512 + lane * 8];
            const half8* b1 = (const half8*)&sXF[((np0 + 1) * 4) * 512 + lane * 8];
#pragma unroll
            for (int ks = 0; ks < 4; ++ks) {
                half8 aV = aE[ks * 64];
                half8 aY = aE[ks * 64 + 256];
                half8 bF0 = b0[ks * 64];
                half8 bF1 = b1[ks * 64];
                accv0 = __builtin_amdgcn_mfma_f32_16x16x32_f16(aV, bF0, accv0, 0, 0, 0);
                accy0 = __builtin_amdgcn_mfma_f32_16x16x32_f16(aY, bF0, accy0, 0, 0, 0);
                accv1 = __builtin_amdgcn_mfma_f32_16x16x32_f16(aV, bF1, accv1, 0, 0, 0);
                accy1 = __builtin_amdgcn_mfma_f32_16x16x32_f16(aY, bF1, accy1, 0, 0, 0);
            }
            // ---- activation for both np tiles: lane owns f = ft*4+q
            int f = ft * 4 + q;
            float invs = sISL[f];
            float slam = sISL[48 + f];
#pragma unroll
            for (int h = 0; h < 2; ++h) {
                int np = np0 + h;
                floatx4 accv = h ? accv1 : accv0;
                floatx4 accy = h ? accy1 : accy0;
                float v[4] = {accv[0] * invs, accv[1] * invs, accv[2] * invs, accv[3] * invs};
                float y[4] = {accy[0] * invs, accy[1] * invs, accy[2] * invs, accy[3] * invs};
                float pv[4]; proj4(v, pv);
                float py[4]; proj4(y, py);
                half4 au, am;
#pragma unroll
                for (int g = 0; g < 4; ++g) {
                    au[g] = (_Float16)(fmaf(eps_e, v[g], pv[g]) * slam);
                    am[g] = (_Float16)(fmaf(eps_e, y[g], py[g]) * slam);
                }
                int aw = ((np * 12 + (ft >> 1)) * 64 + ((ft & 1) * 2 + (q >> 1)) * 16 + n) * 8 + (q & 1) * 4;
                *(half4*)&sACT[aw] = au;
                *(half4*)&sACT[aw + 3072] = am;
            }
        }
        __syncthreads();   // act ready; all pass-1 x reads done
        // ---- pass 2: wave owns cmt = wv, all 4 np tiles; K=384; A loaded once per ks
        floatx4 acc2[4];
#pragma unroll
        for (int np = 0; np < 4; ++np) acc2[np] = (floatx4){0.f, 0.f, 0.f, 0.f};
        {
            const half8* a2F = (const half8*)(wsu + P2_U + (wv * 12) * 512 + lane * 8);
            const half8* bAp = (const half8*)&sACT[lane * 8];
#pragma unroll
            for (int ks = 0; ks < 12; ++ks) {
                half8 aF = a2F[ks * 64];
#pragma unroll
                for (int np = 0; np < 4; ++np) {
                    half8 bA = bAp[(np * 12 + ks) * 64];
                    acc2[np] = __builtin_amdgcn_mfma_f32_16x16x32_f16(aF, bA, acc2[np], 0, 0, 0);
                }
            }
        }
        // ---- update: thread owns (cmt=wv, q, np 0..3); x lives in regs (f32)
        const bool last = (it == niter - 1);
#pragma unroll
        for (int np = 0; np < 4; ++np) {
            int p = np * 16 + n;
            half4 nx4;
#pragma unroll
            for (int l = 0; l < 4; ++l) {
                float xo = xr[np * 4 + l];
                float nx = xo - ((xo - xnr[np * 4 + l]) + acc2[np][l]) * invden;
                xr[np * 4 + l] = nx;
                nx4[l] = (_Float16)nx;
                if (last) oimg[(wv * 16 + q * 4 + l) * HW + p] = nx;
            }
            int xu = ((np * 4 + (wv >> 1)) * 64 + ((wv & 1) * 2 + (q >> 1)) * 16 + n) * 8 + (q & 1) * 4;
            *(half4*)&sXF[xu] = nx4;
        }
    }
}

extern "C" void kernel_launch(void* const* d_in, const int* in_sizes, int n_in,
                              void* d_out, int out_size, void* d_ws, size_t ws_size,
                              hipStream_t stream) {
    const float* x_noisy = (const float*)d_in[0];
    const float* sigma   = (const float*)d_in[1];
    const float* Qp      = (const float*)d_in[2];
    const float* taus_p  = (const float*)d_in[3];
    const float* lamb    = (const float*)d_in[4];
    const float* eps_om  = (const float*)d_in[5];
    const float* mw1     = (const float*)d_in[6];
    const float* mb1     = (const float*)d_in[7];
    const float* mw2     = (const float*)d_in[8];
    const float* mb2     = (const float*)d_in[9];
    const float* mw3     = (const float*)d_in[10];
    const float* mb3     = (const float*)d_in[11];
    const float* Wf      = (const float*)d_in[12];
    const int*   n_iter  = (const int*)d_in[13];
    float* out = (float*)d_out;
    float* ws  = (float*)d_ws;

    hipLaunchKernelGGL(setup_math, dim3(1), dim3(64), 0, stream,
                       sigma, Qp, taus_p, lamb, eps_om,
                       mw1, mb1, mw2, mb2, mw3, mb3, ws);
    hipLaunchKernelGGL(setup_pack, dim3(192), dim3(TPB), 0, stream, Wf, ws);
    hipLaunchKernelGGL(mfoe_main, dim3(512), dim3(MTPB), 0, stream,
                       x_noisy, ws, out, n_iter);
}